// Round 6
// baseline (378.472 us; speedup 1.0000x reference)
//
#include <hip/hip_runtime.h>

#define RADIUS 5
#define WIN 9
#define BB 4
#define KK 4
#define HH 224
#define WW 224
#define HW (HH * WW)
#define PD 234                 // HH + 2*RADIUS
#define PAREA (PD * PD)        // 54756
#define NBUCKET 64
#define PARTIAL_FLOATS (NBUCKET * BB * 8)   // 2048 floats
#define CTRL_FLOATS 2056                    // 2048 partials + counter + pad
#define PSEG_OFF 2560                       // float offset of pseg in d_ws (16B aligned)

#define PX_PER_BLOCK 64
#define BLOCKS_TOTAL (BB * HW / PX_PER_BLOCK)   // 3136
#define WF4_PER_BLOCK (PX_PER_BLOCK * 81 / 4)   // 1296 float4 of weights per block

// ---------- pad + zero control region ----------
__global__ __launch_bounds__(256) void ncuts_pad(
    const float* __restrict__ seg, float4* __restrict__ pseg,
    float* __restrict__ ctrl)
{
    const int tid = blockIdx.x * 256 + threadIdx.x;
    if (tid < CTRL_FLOATS) ctrl[tid] = 0.0f;     // partials + last-block counter
    if (tid >= BB * PAREA) return;
    const int b  = tid / PAREA;
    const int rc = tid - b * PAREA;
    const int r  = rc / PD;
    const int c  = rc - r * PD;
    const int hh = r - RADIUS;
    const int ww = c - RADIUS;
    float4 v = {0.f, 0.f, 0.f, 0.f};
    if (hh >= 0 && hh < HH && ww >= 0 && ww < WW) {
        const float* sb = seg + (size_t)b * KK * HW + hh * WW + ww;
        v.x = sb[0 * HW];
        v.y = sb[1 * HW];
        v.z = sb[2 * HW];
        v.w = sb[3 * HW];
    }
    pseg[tid] = v;
}

// tap range [T0,T1) with compile-time (m,n)
template<int T0, int T1>
__device__ __forceinline__ void do_taps(const float* __restrict__ wl,
                                        const float4* __restrict__ pb, int roff,
                                        float& a0, float& a1, float& a2, float& a3,
                                        float& wsum)
{
    #pragma unroll
    for (int tap = T0; tap < T1; ++tap) {
        const int m = tap / 9;
        const int n = tap - 9 * m;
        const float wv = wl[tap];                 // ds_read_b32, imm offset
        const float4 s = pb[roff + m * PD + n];   // lane-consecutive float4 (cache hit)
        a0 = fmaf(wv, s.x, a0);
        a1 = fmaf(wv, s.y, a1);
        a2 = fmaf(wv, s.z, a2);
        a3 = fmaf(wv, s.w, a3);
        wsum += wv;
    }
}

// ---------- main: 64 px/block, DMA-staged weights, taps split across 4 waves,
//                  last block folds buckets and writes the loss ----------
__global__ __launch_bounds__(256, 7) void ncuts_main(
    const float4* __restrict__ weight4,
    const float4* __restrict__ pseg,
    float* __restrict__ partial,
    int* __restrict__ counter,
    float* __restrict__ out)
{
    __shared__ float wlds[PX_PER_BLOCK * 81];   // 20736 B
    __shared__ float xred[32];
    __shared__ int lastflag;

    const int tid  = threadIdx.x;
    const int lane = tid & 63;
    const int ws   = tid >> 6;

    // --- stage the block's 20.7 KB weight slab via global->LDS DMA (width 16) ---
    const float4* wsrc = weight4 + (size_t)blockIdx.x * WF4_PER_BLOCK;
    float4* wlds4 = (float4*)wlds;
    #pragma unroll
    for (int it = 0; it < 5; ++it) {
        const int base = it * 256 + ws * 64;             // wave-uniform float4 idx
        __builtin_amdgcn_global_load_lds(
            (const __attribute__((address_space(1))) void*)(wsrc + base + lane),
            (__attribute__((address_space(3))) void*)(wlds4 + base),
            16, 0, 0);
    }
    if (tid < 16)                                        // tail: 1296 - 1280
        wlds4[1280 + tid] = wsrc[1280 + tid];
    __syncthreads();   // drains vmcnt (DMA) + lgkmcnt before LDS reads

    // --- per-lane pixel ---
    const int px  = blockIdx.x * PX_PER_BLOCK + lane;
    const int b   = px / HW;                    // block-uniform
    const int rem = px - b * HW;
    const int h   = rem / WW;
    const int w   = rem - h * WW;
    const int roff = h * PD + w;

    const float4* pb = pseg + (size_t)b * PAREA;
    const float* wl  = &wlds[lane * 81];

    float a0 = 0.f, a1 = 0.f, a2 = 0.f, a3 = 0.f, wsum = 0.f;

    switch (ws) {                                // wave-uniform branch
        case 0: do_taps< 0, 21>(wl, pb, roff, a0, a1, a2, a3, wsum); break;
        case 1: do_taps<21, 41>(wl, pb, roff, a0, a1, a2, a3, wsum); break;
        case 2: do_taps<41, 61>(wl, pb, roff, a0, a1, a2, a3, wsum); break;
        default: do_taps<61, 81>(wl, pb, roff, a0, a1, a2, a3, wsum); break;
    }

    const float4 o = pb[roff + RADIUS * PD + RADIUS];   // own pixel

    float vals[8] = { a0 * o.x, a1 * o.y, a2 * o.z, a3 * o.w,
                      wsum * o.x, wsum * o.y, wsum * o.z, wsum * o.w };

    #pragma unroll
    for (int i = 0; i < 8; ++i) {
        float v = vals[i];
        v += __shfl_down(v, 32);
        v += __shfl_down(v, 16);
        v += __shfl_down(v, 8);
        v += __shfl_down(v, 4);
        v += __shfl_down(v, 2);
        v += __shfl_down(v, 1);
        vals[i] = v;
    }

    if (lane == 0) {
        const int bucket = (blockIdx.x * 4 + ws) & (NBUCKET - 1);
        float* dst = partial + (bucket * BB + b) * 8;
        #pragma unroll
        for (int i = 0; i < 8; ++i)
            atomicAdd(dst + i, vals[i]);
    }

    // --- last-block-done: fold buckets, compute loss ---
    __threadfence();                             // release my partial adds
    if (tid == 0) {
        const int c = atomicAdd(counter, 1);     // device-scope (G12)
        lastflag = (c == BLOCKS_TOTAL - 1);
    }
    __syncthreads();
    if (!lastflag) return;

    __threadfence();                             // acquire side
    if (tid < 32) {
        const int bb = tid >> 3;
        const int i  = tid & 7;
        float s = 0.f;
        for (int bucket = 0; bucket < NBUCKET; ++bucket)
            s += __hip_atomic_load(&partial[(bucket * BB + bb) * 8 + i],
                                   __ATOMIC_RELAXED, __HIP_MEMORY_SCOPE_AGENT);
        xred[bb * 8 + i] = s;
    }
    __syncthreads();
    if (tid == 0) {
        float total = 0.f;
        for (int bb = 0; bb < BB; ++bb) {
            float assoc = 0.f;
            for (int k = 0; k < KK; ++k)
                assoc += xred[bb * 8 + k] / xred[bb * 8 + 4 + k];
            total += (float)KK - assoc;
        }
        out[0] = total;
    }
}

extern "C" void kernel_launch(void* const* d_in, const int* in_sizes, int n_in,
                              void* d_out, int out_size, void* d_ws, size_t ws_size,
                              hipStream_t stream) {
    const float* seg     = (const float*)d_in[0];
    const float4* weight = (const float4*)d_in[1];
    float* out     = (float*)d_out;
    float* wsf     = (float*)d_ws;
    float* partial = wsf;                          // 2048 floats
    int*   counter = (int*)(wsf + 2048);
    float4* pseg   = (float4*)(wsf + PSEG_OFF);    // byte offset 10240, 16B aligned

    {
        const int total = BB * PAREA;              // 219024
        const int grid  = (total + 255) / 256;     // 856
        hipLaunchKernelGGL(ncuts_pad, dim3(grid), dim3(256), 0, stream,
                           seg, pseg, wsf);
    }
    hipLaunchKernelGGL(ncuts_main, dim3(BLOCKS_TOTAL), dim3(256), 0, stream,
                       weight, pseg, partial, counter, out);
}

// Round 7
// 244.804 us; speedup vs baseline: 1.5460x; 1.5460x over previous
//
#include <hip/hip_runtime.h>

#define RADIUS 5
#define WIN 9
#define BB 4
#define KK 4
#define HH 224
#define WW 224
#define HW (HH * WW)
#define PD 234                 // HH + 2*RADIUS
#define PAREA (PD * PD)        // 54756
#define NBUCKET 64
#define PARTIAL_FLOATS (NBUCKET * BB * 8)   // 2048 floats

#define CHUNK 1024                          // weight elements per wave
#define ITERS 16                            // 1024 / 64
#define WAVES_PER_B (HW * 81 / CHUNK)       // 3969 (exact)
#define WAVES_TOTAL (BB * WAVES_PER_B)      // 15876
#define BLOCKS_TOTAL (WAVES_TOTAL / 4)      // 3969

// d_ws layout (floats):
//   [0, 2048)   : partial buckets [bucket][b][8] (0..3 A_k, 4..7 V_k)
//   [2048, ...) : padded seg P[b][r][c][k] as float4 per (r,c)  (byte off 8192)

// ---------- pad + zero partials ----------
__global__ __launch_bounds__(256) void ncuts_pad(
    const float* __restrict__ seg, float4* __restrict__ pseg,
    float* __restrict__ ctrl)
{
    const int tid = blockIdx.x * 256 + threadIdx.x;
    if (tid < PARTIAL_FLOATS) ctrl[tid] = 0.0f;
    if (tid >= BB * PAREA) return;
    const int b  = tid / PAREA;
    const int rc = tid - b * PAREA;
    const int r  = rc / PD;
    const int c  = rc - r * PD;
    const int hh = r - RADIUS;
    const int ww = c - RADIUS;
    float4 v = {0.f, 0.f, 0.f, 0.f};
    if (hh >= 0 && hh < HH && ww >= 0 && ww < WW) {
        const float* sb = seg + (size_t)b * KK * HW + hh * WW + ww;
        v.x = sb[0 * HW];
        v.y = sb[1 * HW];
        v.z = sb[2 * HW];
        v.w = sb[3 * HW];
    }
    pseg[tid] = v;
}

// ---------- main: flat-order weight stream, 16 preloaded weights/wave ----------
// wave wid owns weight elements [wid*1024, (wid+1)*1024), entirely within one b.
// iteration t: lane L handles element t*64 + L of the chunk.
__global__ __launch_bounds__(256, 6) void ncuts_main(
    const float* __restrict__ weight,
    const float4* __restrict__ pseg,
    float* __restrict__ partial)
{
    const int lane = threadIdx.x & 63;
    const int wid  = blockIdx.x * 4 + (threadIdx.x >> 6);   // 0..15875
    const int b    = wid / WAVES_PER_B;                     // wave-uniform

    const float* wb  = weight + (size_t)wid * CHUNK;
    const float4* pb = pseg + (size_t)b * PAREA;

    // --- preload the wave's entire 4 KB weight slice: 16 independent loads ---
    float wv[ITERS];
    #pragma unroll
    for (int t = 0; t < ITERS; ++t)
        wv[t] = wb[t * 64 + lane];          // 256 B coalesced per wave-instr

    // --- initial per-lane decode: element e0 = wid*1024 + lane ---
    const uint32_t e0  = (uint32_t)wid * CHUNK + (uint32_t)lane;
    const uint32_t px  = e0 / 81u;
    int tap            = (int)(e0 - 81u * px);
    const uint32_t rem = px - (uint32_t)b * HW;
    uint32_t h         = rem / (uint32_t)WW;
    uint32_t w         = rem - h * (uint32_t)WW;
    int roff           = (int)(h * PD + w);

    float a0 = 0.f, a1 = 0.f, a2 = 0.f, a3 = 0.f;
    float v0 = 0.f, v1 = 0.f, v2 = 0.f, v3 = 0.f;

    #pragma unroll
    for (int t = 0; t < ITERS; ++t) {
        const int m = (tap * 57) >> 9;          // tap/9, exact for tap<81
        const int n = tap - 9 * m;
        const float4 s = pb[roff + m * PD + n];             // clustered, cache hit
        const float4 o = pb[roff + (RADIUS * PD + RADIUS)]; // own pixel, cache hit
        const float wt = wv[t];
        a0 = fmaf(wt * s.x, o.x, a0);
        a1 = fmaf(wt * s.y, o.y, a1);
        a2 = fmaf(wt * s.z, o.z, a2);
        a3 = fmaf(wt * s.w, o.w, a3);
        v0 = fmaf(wt, o.x, v0);
        v1 = fmaf(wt, o.y, v1);
        v2 = fmaf(wt, o.z, v2);
        v3 = fmaf(wt, o.w, v3);

        // advance element by 64: tap wraps at most once (64 < 81)
        tap += 64;
        if (tap >= 81) {
            tap -= 81;
            const bool roww = (w == WW - 1);
            w = roww ? 0 : w + 1;
            h += roww ? 1 : 0;
            roff += roww ? (PD - WW + 1) : 1;
        }
    }

    float vals[8] = { a0, a1, a2, a3, v0, v1, v2, v3 };

    #pragma unroll
    for (int i = 0; i < 8; ++i) {
        float v = vals[i];
        v += __shfl_down(v, 32);
        v += __shfl_down(v, 16);
        v += __shfl_down(v, 8);
        v += __shfl_down(v, 4);
        v += __shfl_down(v, 2);
        v += __shfl_down(v, 1);
        vals[i] = v;
    }

    if (lane == 0) {
        const int bucket = wid & (NBUCKET - 1);
        float* dst = partial + (bucket * BB + b) * 8;
        #pragma unroll
        for (int i = 0; i < 8; ++i)
            atomicAdd(dst + i, vals[i]);
    }
}

// ---------- final: fold buckets, compute loss ----------
__global__ __launch_bounds__(64) void ncuts_final(
    const float* __restrict__ partial, float* __restrict__ out)
{
    __shared__ float sums[32];
    const int t = threadIdx.x;
    if (t < 32) {
        const int b = t >> 3;
        const int i = t & 7;
        float s = 0.f;
        for (int bucket = 0; bucket < NBUCKET; ++bucket)
            s += partial[(bucket * BB + b) * 8 + i];
        sums[b * 8 + i] = s;
    }
    __syncthreads();
    if (t == 0) {
        float total = 0.f;
        for (int b = 0; b < BB; ++b) {
            float assoc = 0.f;
            for (int k = 0; k < KK; ++k) {
                const float A = sums[b * 8 + k];
                const float V = sums[b * 8 + 4 + k];
                assoc += A / V;
            }
            total += (float)KK - assoc;
        }
        out[0] = total;
    }
}

extern "C" void kernel_launch(void* const* d_in, const int* in_sizes, int n_in,
                              void* d_out, int out_size, void* d_ws, size_t ws_size,
                              hipStream_t stream) {
    const float* seg    = (const float*)d_in[0];
    const float* weight = (const float*)d_in[1];
    float* out     = (float*)d_out;
    float* wsf     = (float*)d_ws;
    float* partial = wsf;                              // 2048 floats
    float4* pseg   = (float4*)(wsf + PARTIAL_FLOATS);  // byte offset 8192, 16B aligned

    {
        const int total = BB * PAREA;              // 219024
        const int grid  = (total + 255) / 256;     // 856
        hipLaunchKernelGGL(ncuts_pad, dim3(grid), dim3(256), 0, stream,
                           seg, pseg, partial);
    }
    hipLaunchKernelGGL(ncuts_main, dim3(BLOCKS_TOTAL), dim3(256), 0, stream,
                       weight, pseg, partial);
    hipLaunchKernelGGL(ncuts_final, dim3(1), dim3(64), 0, stream, partial, out);
}